// Round 4
// baseline (2503.457 us; speedup 1.0000x reference)
//
#include <hip/hip_runtime.h>
#include <hip/hip_bf16.h>
#include <stdint.h>

#define DM 512
#define DFF 2048
#define NH 8
#define DKH 64
#define NL 6
#define BB 4
#define SSQ 512
#define ROWS (BB*SSQ)      // 2048
#define NEGV -1000000000.0f
#define EPSV 1e-5f

typedef __attribute__((ext_vector_type(8))) short bf16x8;   // 8 bf16 = 4 VGPR
typedef __attribute__((ext_vector_type(4))) float f32x4;
typedef unsigned short u16;

// ---- bf16 split helpers (RNE) ----------------------------------------------
__device__ __forceinline__ u16 f2bf(float x) {
    uint32_t b = __float_as_uint(x);
    b += 0x7FFFu + ((b >> 16) & 1u);
    return (u16)(b >> 16);
}
__device__ __forceinline__ float bf2f(u16 u) {
    return __uint_as_float(((uint32_t)u) << 16);
}
__device__ __forceinline__ void split2(float x, u16& hi, u16& lo) {
    hi = f2bf(x);
    lo = f2bf(x - bf2f(hi));     // residual; |lo| <~ 2^-9 |x|
}

// ============================================================================
// Split-bf16 MFMA GEMM.  C = op(A)@op(B) via Ahi*Bhi + Ahi*Blo + Alo*Bhi
// (fp32 accum; rel err ~1e-5).  A planes: [M][K] row-major bf16 (shared lda).
// B planes: [N][K] row-major bf16 (B^T layout; shared ldb).
// 256 thr / 4 waves (2x2), BK=32, 2-barrier loop, global_load_lds width-16
// staging with both-sides XOR swizzle (slot ^= (row>>1)&3): 64B-row
// ds_read_b128 becomes ~2-way (free, m136) instead of 4-way.
// EPI_F32: scale+causal -> fp32 C.  EPI_SPLIT: bf16 hi/lo planes (+ReLU opt).
// Batched via gridDim.z: z -> (zb=z/batH, zh=z%batH), strides per operand.
// ============================================================================
#define EPI_F32 0
#define EPI_SPLIT 1

template<int BM, int BN, int EPI, bool RELU>
__global__ __launch_bounds__(256, (BM==64)?3:2)
void mgemm_k(const u16* __restrict__ Ahi, const u16* __restrict__ Alo,
             const u16* __restrict__ Bhi, const u16* __restrict__ Blo,
             float* __restrict__ C, u16* __restrict__ Chi, u16* __restrict__ Clo,
             int K, int lda, int ldb, int ldc,
             int batH, long sAb, long sAh, long sBb, long sBh, long sCb, long sCh,
             float scale, int causal)
{
    constexpr int FM = BM/32, FN = BN/32;        // 16x16 frags per wave
    constexpr int CA = BM/16, CB = BN/16;        // 16-row staging chunks
    constexpr int NC = 2*(CA+CB);                // total chunks (4 planes)
    __shared__ u16 lds[(2*BM + 2*BN)*32];
    u16* sAhi = lds;
    u16* sAlo = lds + BM*32;
    u16* sBhi = lds + 2*BM*32;
    u16* sBlo = lds + 2*BM*32 + BN*32;

    {
        const int z  = blockIdx.z;
        const int zb = z / batH, zh = z % batH;
        Ahi += (long)zb*sAb + (long)zh*sAh;  Alo += (long)zb*sAb + (long)zh*sAh;
        Bhi += (long)zb*sBb + (long)zh*sBh;  Blo += (long)zb*sBb + (long)zh*sBh;
        const long co = (long)zb*sCb + (long)zh*sCh;
        if (C)   C   += co;
        if (Chi) { Chi += co; Clo += co; }
    }

    const int tid  = threadIdx.x;
    const int wave = tid >> 6, lane = tid & 63;
    const int rowBase = blockIdx.y * BM;
    const int colBase = blockIdx.x * BN;
    // staging lane coords: 16 rows x 4 slots(16B) per chunk; pre-swizzle source
    const int sr    = lane >> 2;                        // row in chunk
    const int sslot = (lane & 3) ^ ((sr >> 1) & 3);     // global k-chunk to fetch
    // compute lane coords
    const int fr = lane & 15, ks = lane >> 4;
    const int wrow0 = (wave >> 1) * (BM/2);
    const int wcol0 = (wave & 1)  * (BN/2);
    const int rsw   = (ks ^ ((fr >> 1) & 3)) * 8;       // swizzled k-slot (elems)

    f32x4 acc[FM][FN];
    const f32x4 zero = {0.f, 0.f, 0.f, 0.f};
#pragma unroll
    for (int i = 0; i < FM; ++i)
#pragma unroll
        for (int j = 0; j < FN; ++j) acc[i][j] = zero;

    for (int kt = 0; kt < K; kt += 32) {
        __syncthreads();                       // prior compute done reading LDS
#pragma unroll
        for (int cc = 0; cc < NC/4; ++cc) {
            const int c = wave + cc*4;
            const u16* src; u16* dst; int grow; int ld;
            if (c < CA)           { src=Ahi; dst=sAhi + c*512;           grow=rowBase + c*16;           ld=lda; }
            else if (c < 2*CA)    { src=Alo; dst=sAlo + (c-CA)*512;      grow=rowBase + (c-CA)*16;      ld=lda; }
            else if (c < 2*CA+CB) { src=Bhi; dst=sBhi + (c-2*CA)*512;    grow=colBase + (c-2*CA)*16;    ld=ldb; }
            else                  { src=Blo; dst=sBlo + (c-2*CA-CB)*512; grow=colBase + (c-2*CA-CB)*16; ld=ldb; }
            const u16* g = src + (long)(grow + sr)*ld + kt + sslot*8;
            __builtin_amdgcn_global_load_lds(
                (const __attribute__((address_space(1))) void*)g,
                (__attribute__((address_space(3))) void*)dst, 16, 0, 0);
        }
        __syncthreads();                       // drains vmcnt before compute

        bf16x8 ah[FM], al[FM], bh[FN], bl[FN];
#pragma unroll
        for (int i = 0; i < FM; ++i) {
            const int off = (wrow0 + i*16 + fr)*32 + rsw;
            ah[i] = *(const bf16x8*)(sAhi + off);
            al[i] = *(const bf16x8*)(sAlo + off);
        }
#pragma unroll
        for (int j = 0; j < FN; ++j) {
            const int off = (wcol0 + j*16 + fr)*32 + rsw;
            bh[j] = *(const bf16x8*)(sBhi + off);
            bl[j] = *(const bf16x8*)(sBlo + off);
        }
#pragma unroll
        for (int i = 0; i < FM; ++i)
#pragma unroll
            for (int j = 0; j < FN; ++j) {
                acc[i][j] = __builtin_amdgcn_mfma_f32_16x16x32_bf16(ah[i], bh[j], acc[i][j], 0, 0, 0);
                acc[i][j] = __builtin_amdgcn_mfma_f32_16x16x32_bf16(ah[i], bl[j], acc[i][j], 0, 0, 0);
                acc[i][j] = __builtin_amdgcn_mfma_f32_16x16x32_bf16(al[i], bh[j], acc[i][j], 0, 0, 0);
            }
    }

    // epilogue — C/D layout: col = lane&15, row = (lane>>4)*4 + reg   [m89]
    const int er = lane >> 4, ec = lane & 15;
#pragma unroll
    for (int i = 0; i < FM; ++i)
#pragma unroll
        for (int j = 0; j < FN; ++j) {
            const int gc = colBase + wcol0 + j*16 + ec;
#pragma unroll
            for (int q = 0; q < 4; ++q) {
                const int gr = rowBase + wrow0 + i*16 + er*4 + q;
                float x = acc[i][j][q];
                if constexpr (EPI == EPI_F32) x *= scale;
                if (EPI == EPI_F32 && causal && gc > gr) x = NEGV;
                if constexpr (RELU) x = fmaxf(x, 0.f);
                const long off = (long)gr*ldc + gc;
                if constexpr (EPI == EPI_F32) C[off] = x;
                else { u16 h, l; split2(x, h, l); Chi[off] = h; Clo[off] = l; }
            }
        }
}

// ---------------------------------------------------------------------------
__device__ __forceinline__ float waveSum(float v) {
#pragma unroll
    for (int off = 32; off > 0; off >>= 1) v += __shfl_xor(v, off);
    return v;
}
__device__ __forceinline__ float waveMax(float v) {
#pragma unroll
    for (int off = 32; off > 0; off >>= 1) v = fmaxf(v, __shfl_xor(v, off));
    return v;
}

// softmax over 512-wide fp32 rows, IN PLACE: row's 2048B footprint is rewritten
// as [512 u16 hi-plane][512 u16 lo-plane].  Safe: every lane's loads complete
// (waitcnt before the shuffle-reduce) before any store issues; rows don't
// cross wave boundaries.
__global__ __launch_bounds__(256) void softmax_k(float* __restrict__ s)
{
    const int lane = threadIdx.x & 63;
    const int wv   = threadIdx.x >> 6;
    const long row = (long)blockIdx.x * 4 + wv;
    float* pr = s + row * SSQ;

    float4 x0 = *(const float4*)(pr + lane*8);
    float4 x1 = *(const float4*)(pr + lane*8 + 4);
    float v[8] = {x0.x, x0.y, x0.z, x0.w, x1.x, x1.y, x1.z, x1.w};

    float mx = v[0];
#pragma unroll
    for (int i = 1; i < 8; ++i) mx = fmaxf(mx, v[i]);
    mx = waveMax(mx);
    float sum = 0.f;
#pragma unroll
    for (int i = 0; i < 8; ++i) { v[i] = __expf(v[i] - mx); sum += v[i]; }
    sum = waveSum(sum);
    const float inv = 1.f / sum;

    u16 h[8], l[8];
#pragma unroll
    for (int i = 0; i < 8; ++i) split2(v[i]*inv, h[i], l[i]);
    u16* oh = (u16*)pr + lane*8;          // hi plane: bytes [0,1024) of row
    u16* ol = (u16*)pr + 512 + lane*8;    // lo plane: bytes [1024,2048)
    *(ushort4*)(oh)     = make_ushort4(h[0], h[1], h[2], h[3]);
    *(ushort4*)(oh + 4) = make_ushort4(h[4], h[5], h[6], h[7]);
    *(ushort4*)(ol)     = make_ushort4(l[0], l[1], l[2], l[3]);
    *(ushort4*)(ol + 4) = make_ushort4(l[4], l[5], l[6], l[7]);
}

// out = LayerNorm(x + (resH+resL)); planes in/out (out may alias res: each
// lane rewrites exactly the u16s it read).  Optional fp32 out (final output).
__global__ __launch_bounds__(256) void ln_k(const float* __restrict__ x,
                                            const u16* __restrict__ resH,
                                            const u16* __restrict__ resL,
                                            u16* __restrict__ oH,
                                            u16* __restrict__ oL,
                                            float* __restrict__ outF)
{
    const int lane = threadIdx.x & 63;
    const int wv   = threadIdx.x >> 6;
    const long row = (long)blockIdx.x * 4 + wv;
    const float* px = x + row * DM;

    float4 a0 = *(const float4*)(px + lane*8);
    float4 a1 = *(const float4*)(px + lane*8 + 4);
    ushort4 rh0 = *(const ushort4*)(resH + row*DM + lane*8);
    ushort4 rh1 = *(const ushort4*)(resH + row*DM + lane*8 + 4);
    ushort4 rl0 = *(const ushort4*)(resL + row*DM + lane*8);
    ushort4 rl1 = *(const ushort4*)(resL + row*DM + lane*8 + 4);
    float v[8] = {a0.x + bf2f(rh0.x)+bf2f(rl0.x), a0.y + bf2f(rh0.y)+bf2f(rl0.y),
                  a0.z + bf2f(rh0.z)+bf2f(rl0.z), a0.w + bf2f(rh0.w)+bf2f(rl0.w),
                  a1.x + bf2f(rh1.x)+bf2f(rl1.x), a1.y + bf2f(rh1.y)+bf2f(rl1.y),
                  a1.z + bf2f(rh1.z)+bf2f(rl1.z), a1.w + bf2f(rh1.w)+bf2f(rl1.w)};

    float s = 0.f;
#pragma unroll
    for (int i = 0; i < 8; ++i) s += v[i];
    s = waveSum(s);
    const float mean = s * (1.f / DM);
    float s2 = 0.f;
#pragma unroll
    for (int i = 0; i < 8; ++i) { float d = v[i] - mean; s2 += d*d; }
    s2 = waveSum(s2);
    const float rstd = rsqrtf(s2 * (1.f / DM) + EPSV);

    float o[8]; u16 h[8], l[8];
#pragma unroll
    for (int i = 0; i < 8; ++i) { o[i] = (v[i]-mean)*rstd; split2(o[i], h[i], l[i]); }
    u16* ph = oH + row*DM + lane*8;
    u16* pl = oL + row*DM + lane*8;
    *(ushort4*)(ph)     = make_ushort4(h[0], h[1], h[2], h[3]);
    *(ushort4*)(ph + 4) = make_ushort4(h[4], h[5], h[6], h[7]);
    *(ushort4*)(pl)     = make_ushort4(l[0], l[1], l[2], l[3]);
    *(ushort4*)(pl + 4) = make_ushort4(l[4], l[5], l[6], l[7]);
    if (outF) {
        float* po = outF + row*DM;
        *(float4*)(po + lane*8)     = make_float4(o[0], o[1], o[2], o[3]);
        *(float4*)(po + lane*8 + 4) = make_float4(o[4], o[5], o[6], o[7]);
    }
}

// fp32 input -> bf16 hi/lo planes
__global__ __launch_bounds__(256) void prep_k(const float* __restrict__ in,
                                              u16* __restrict__ oHi,
                                              u16* __restrict__ oLo, int n4)
{
    const int i = blockIdx.x*256 + threadIdx.x;
    if (i >= n4) return;
    float4 v = ((const float4*)in)[i];
    u16 h[4], l[4];
    split2(v.x, h[0], l[0]); split2(v.y, h[1], l[1]);
    split2(v.z, h[2], l[2]); split2(v.w, h[3], l[3]);
    ((ushort4*)oHi)[i] = make_ushort4(h[0], h[1], h[2], h[3]);
    ((ushort4*)oLo)[i] = make_ushort4(l[0], l[1], l[2], l[3]);
}

// transpose-convert fp32 weights: out[c][r] = split(in[r][c]); 32x32 tiles
__global__ __launch_bounds__(256) void tconv_k(
    const float* __restrict__ in, u16* __restrict__ oHi, u16* __restrict__ oLo,
    int ldin, int ldout, long sIn, long sOut)
{
    const int z = blockIdx.z;
    in  += (long)z*sIn;
    oHi += (long)z*sOut;
    oLo += (long)z*sOut;
    __shared__ float t[32][33];
    const int tid = threadIdx.x;
    const int r0 = blockIdx.y*32, c0 = blockIdx.x*32;
    {
        const int ir = tid >> 3, ic = (tid & 7) * 4;
        const float4 v = *(const float4*)(in + (long)(r0+ir)*ldin + c0 + ic);
        t[ir][ic+0]=v.x; t[ir][ic+1]=v.y; t[ir][ic+2]=v.z; t[ir][ic+3]=v.w;
    }
    __syncthreads();
    {
        const int orr = tid >> 3, oc = (tid & 7) * 4;
        u16 h[4], l[4];
#pragma unroll
        for (int i = 0; i < 4; ++i) split2(t[oc+i][orr], h[i], l[i]);
        *(ushort4*)(oHi + (long)(c0+orr)*ldout + r0 + oc) = make_ushort4(h[0],h[1],h[2],h[3]);
        *(ushort4*)(oLo + (long)(c0+orr)*ldout + r0 + oc) = make_ushort4(l[0],l[1],l[2],l[3]);
    }
}

// plane transpose (u16 hi/lo pair), batched: out[c][r] = in[r][c]
__global__ __launch_bounds__(256) void tconvp_k(
    const u16* __restrict__ iH, const u16* __restrict__ iL,
    u16* __restrict__ oH, u16* __restrict__ oL,
    int ldin, int ldout, int batH,
    long sInB, long sInH, long sOutB, long sOutH)
{
    const int z = blockIdx.z, zb = z / batH, zh = z % batH;
    iH += (long)zb*sInB  + (long)zh*sInH;
    iL += (long)zb*sInB  + (long)zh*sInH;
    oH += (long)zb*sOutB + (long)zh*sOutH;
    oL += (long)zb*sOutB + (long)zh*sOutH;
    __shared__ u16 tH[32][36], tL[32][36];
    const int tid = threadIdx.x;
    const int r0 = blockIdx.y*32, c0 = blockIdx.x*32;
    {
        const int ir = tid >> 3, ic = (tid & 7) * 4;
        *(ushort4*)&tH[ir][ic] = *(const ushort4*)(iH + (long)(r0+ir)*ldin + c0 + ic);
        *(ushort4*)&tL[ir][ic] = *(const ushort4*)(iL + (long)(r0+ir)*ldin + c0 + ic);
    }
    __syncthreads();
    {
        const int orr = tid >> 3, oc = (tid & 7) * 4;
        ushort4 h = make_ushort4(tH[oc+0][orr], tH[oc+1][orr], tH[oc+2][orr], tH[oc+3][orr]);
        ushort4 l = make_ushort4(tL[oc+0][orr], tL[oc+1][orr], tL[oc+2][orr], tL[oc+3][orr]);
        *(ushort4*)(oH + (long)(c0+orr)*ldout + r0 + oc) = h;
        *(ushort4*)(oL + (long)(c0+orr)*ldout + r0 + oc) = l;
    }
}

// ---------------------------------------------------------------------------
extern "C" void kernel_launch(void* const* d_in, const int* in_sizes, int n_in,
                              void* d_out, int out_size, void* d_ws, size_t ws_size,
                              hipStream_t stream)
{
    (void)in_sizes; (void)n_in; (void)out_size; (void)ws_size;

    const float* enc_in = (const float*)d_in[0];
    const float* dec_in = (const float*)d_in[1];
    // d_in[2]: tril mask — replicated analytically via `causal`
    const float* enc_Wq = (const float*)d_in[3];
    const float* enc_Wk = (const float*)d_in[4];
    const float* enc_Wv = (const float*)d_in[5];
    const float* enc_Wo = (const float*)d_in[6];
    const float* enc_W1 = (const float*)d_in[7];
    const float* enc_W2 = (const float*)d_in[8];
    const float* sa_Wq  = (const float*)d_in[9];
    const float* sa_Wk  = (const float*)d_in[10];
    const float* sa_Wv  = (const float*)d_in[11];
    const float* sa_Wo  = (const float*)d_in[12];
    const float* ca_Wq  = (const float*)d_in[13];
    const float* ca_Wk  = (const float*)d_in[14];
    const float* ca_Wv  = (const float*)d_in[15];
    const float* ca_Wo  = (const float*)d_in[16];
    const float* dec_W1 = (const float*)d_in[17];
    const float* dec_W2 = (const float*)d_in[18];

    // ---- ws allocator (256B aligned); total ~168 MB ----
    char* base = (char*)d_ws; size_t off = 0;
    auto alloc = [&](size_t bytes) -> void* {
        off = (off + 255) & ~(size_t)255;
        void* r = base + off; off += bytes; return r;
    };
    auto aU = [&](long n) { return (u16*)  alloc((size_t)n * 2); };
    auto aF = [&](long n) { return (float*)alloc((size_t)n * 4); };

    // phase-unioned weight region: encoder weights, then (after the encoder
    // has fully run) overwritten by decoder weights.  max(75.5, 100.7) MB.
    u16* wreg = aU(50331648L);
    // encoder phase layout
    u16 *eQkvH = wreg,            *eQkvL = wreg + 4718592L;
    u16 *eWoH  = wreg + 9437184L, *eWoL  = wreg + 11010048L;
    u16 *eW1H  = wreg + 12582912L,*eW1L  = wreg + 18874368L;
    u16 *eW2H  = wreg + 25165824L,*eW2L  = wreg + 31457280L;
    // decoder phase layout
    u16 *sQkvH = wreg,            *sQkvL = wreg + 4718592L;
    u16 *sWoH  = wreg + 9437184L, *sWoL  = wreg + 11010048L;
    u16 *cQkvH = wreg + 12582912L,*cQkvL = wreg + 17301504L;
    u16 *cWoH  = wreg + 22020096L,*cWoL  = wreg + 23592960L;
    u16 *dW1H  = wreg + 25165824L,*dW1L  = wreg + 31457280L;
    u16 *dW2H  = wreg + 37748736L,*dW2L  = wreg + 44040192L;

    const long AC = (long)ROWS*DM;                      // 1,048,576
    u16 *hH = aU(AC), *hL = aU(AC);                     // encoder stream planes
    u16 *dH = aU(AC), *dL = aU(AC);                     // decoder stream planes
    u16 *qkvH = aU((long)ROWS*1536), *qkvL = aU((long)ROWS*1536);
    u16 *vtH = aU(AC), *vtL = aU(AC);                   // V^T per head [32][64][512]
    u16 *ctxH = aU(AC), *ctxL = aU(AC);
    float *obuf = aF(AC);
    float *scoresF = aF((long)32*512*512);              // ∪ attn planes ∪ ffn mid
    u16 *midH = (u16*)scoresF, *midL = midH + (long)DFF*DFF;

    // weight transpose-convert: z-batched over layers
    auto tcW = [&](const float* W, u16* oH, u16* oL, int Kd, int Nd,
                   long sOut, long outOff) {
        dim3 g(Nd/32, Kd/32, NL);
        tconv_k<<<g, 256, 0, stream>>>(W, oH + outOff, oL + outOff,
                                       Nd, Kd, (long)Kd*Nd, sOut);
    };

    prep_k<<<AC/4/256, 256, 0, stream>>>(enc_in, hH, hL, AC/4);
    prep_k<<<AC/4/256, 256, 0, stream>>>(dec_in, dH, dL, AC/4);

    // attention core: qkv planes [2048][1536] already filled (Q|K|V)
    auto attn_core = [&](u16* xH, u16* xL, const u16* woH, const u16* woL,
                         int layer, int causal) {
        // scores = (Q @ K^T)/8
        mgemm_k<128,128,EPI_F32,false><<<dim3(4,4,32), 256, 0, stream>>>(
            qkvH, qkvL, qkvH + 512, qkvL + 512, scoresF, nullptr, nullptr,
            64, 1536, 1536, 512,
            8, 786432L, 64, 786432L, 64, (long)8*262144, 262144,
            0.125f, causal);
        softmax_k<<<32*512/4, 256, 0, stream>>>(scoresF);   // -> in-place planes
        // V^T per head (plane transpose of qkv cols 1024..1535)
        tconvp_k<<<dim3(2,16,32), 256, 0, stream>>>(
            qkvH + 1024, qkvL + 1024, vtH, vtL, 1536, 512,
            8, 786432L, 64, (long)8*32768, 32768);
        // ctx = attn @ V  (attn planes live inside scoresF rows: lda=1024)
        const u16* aH = (const u16*)scoresF;
        mgemm_k<64,64,EPI_SPLIT,false><<<dim3(1,8,32), 256, 0, stream>>>(
            aH, aH + 512, vtH, vtL, nullptr, ctxH, ctxL,
            512, 1024, 512, 512,
            8, (long)8*524288, 524288, (long)8*32768, 32768, 262144, 64,
            1.f, 0);
        // o = ctx @ Wo
        mgemm_k<64,64,EPI_F32,false><<<dim3(8,32,1), 256, 0, stream>>>(
            ctxH, ctxL, woH + (long)layer*262144, woL + (long)layer*262144,
            obuf, nullptr, nullptr,
            512, 512, 512, 512, 1, 0,0,0,0,0,0, 1.f, 0);
        ln_k<<<ROWS/4, 256, 0, stream>>>(obuf, xH, xL, xH, xL, nullptr);
    };

    auto ffn = [&](u16* xH, u16* xL, const u16* w1H, const u16* w1L,
                   const u16* w2H, const u16* w2L, int layer, float* outF) {
        const long o1 = (long)layer*DFF*DM;
        mgemm_k<128,128,EPI_SPLIT,true><<<dim3(16,16,1), 256, 0, stream>>>(
            xH, xL, w1H + o1, w1L + o1, nullptr, midH, midL,
            512, 512, 512, 2048, 1, 0,0,0,0,0,0, 1.f, 0);
        mgemm_k<64,64,EPI_F32,false><<<dim3(8,32,1), 256, 0, stream>>>(
            midH, midL, w2H + o1, w2L + o1, obuf, nullptr, nullptr,
            2048, 2048, 2048, 512, 1, 0,0,0,0,0,0, 1.f, 0);
        ln_k<<<ROWS/4, 256, 0, stream>>>(obuf, xH, xL, xH, xL, outF);
    };

    // ======== encoder phase ========
    tcW(enc_Wq, eQkvH, eQkvL, 512, 512, 786432L, 0);
    tcW(enc_Wk, eQkvH, eQkvL, 512, 512, 786432L, 262144L);
    tcW(enc_Wv, eQkvH, eQkvL, 512, 512, 786432L, 524288L);
    tcW(enc_Wo, eWoH, eWoL, 512, 512, 262144L, 0);
    tcW(enc_W1, eW1H, eW1L, 512, 2048, 1048576L, 0);
    tcW(enc_W2, eW2H, eW2L, 2048, 512, 1048576L, 0);

    for (int i = 0; i < NL; ++i) {
        const long ow = (long)i*786432;
        mgemm_k<64,64,EPI_SPLIT,false><<<dim3(24,32,1), 256, 0, stream>>>(
            hH, hL, eQkvH + ow, eQkvL + ow, nullptr, qkvH, qkvL,
            512, 512, 512, 1536, 1, 0,0,0,0,0,0, 1.f, 0);
        attn_core(hH, hL, eWoH, eWoL, i, 0);
        ffn(hH, hL, eW1H, eW1L, eW2H, eW2L, i, nullptr);
    }

    // ======== decoder phase (weights overwrite the encoder region) ========
    tcW(sa_Wq, sQkvH, sQkvL, 512, 512, 786432L, 0);
    tcW(sa_Wk, sQkvH, sQkvL, 512, 512, 786432L, 262144L);
    tcW(sa_Wv, sQkvH, sQkvL, 512, 512, 786432L, 524288L);
    tcW(sa_Wo, sWoH, sWoL, 512, 512, 262144L, 0);
    tcW(ca_Wq, cQkvH, cQkvL, 512, 512, 786432L, 0);
    tcW(ca_Wk, cQkvH, cQkvL, 512, 512, 786432L, 262144L);
    tcW(ca_Wv, cQkvH, cQkvL, 512, 512, 786432L, 524288L);
    tcW(ca_Wo, cWoH, cWoL, 512, 512, 262144L, 0);
    tcW(dec_W1, dW1H, dW1L, 512, 2048, 1048576L, 0);
    tcW(dec_W2, dW2H, dW2L, 2048, 512, 1048576L, 0);

    for (int i = 0; i < NL; ++i) {
        const long ow = (long)i*786432;
        // causal self-attn
        mgemm_k<64,64,EPI_SPLIT,false><<<dim3(24,32,1), 256, 0, stream>>>(
            dH, dL, sQkvH + ow, sQkvL + ow, nullptr, qkvH, qkvL,
            512, 512, 512, 1536, 1, 0,0,0,0,0,0, 1.f, 0);
        attn_core(dH, dL, sWoH, sWoL, i, 1);
        // cross-attn: Q from decoder, K/V from encoder output planes
        mgemm_k<64,64,EPI_SPLIT,false><<<dim3(8,32,1), 256, 0, stream>>>(
            dH, dL, cQkvH + ow, cQkvL + ow, nullptr, qkvH, qkvL,
            512, 512, 512, 1536, 1, 0,0,0,0,0,0, 1.f, 0);
        mgemm_k<64,64,EPI_SPLIT,false><<<dim3(16,32,1), 256, 0, stream>>>(
            hH, hL, cQkvH + ow + 262144, cQkvL + ow + 262144,
            nullptr, qkvH + 512, qkvL + 512,
            512, 512, 512, 1536, 1, 0,0,0,0,0,0, 1.f, 0);
        attn_core(dH, dL, cWoH, cWoL, i, 0);
        // FFN; final layer's LN writes d_out directly
        ffn(dH, dL, dW1H, dW1L, dW2H, dW2L, i,
            (i == NL-1) ? (float*)d_out : nullptr);
    }
}